// Round 6
// baseline (346.510 us; speedup 1.0000x reference)
//
#include <hip/hip_runtime.h>
#include <math.h>

// SSIM loss, (32,3,512,512) fp32, 11x11 sigma=1.5 separable Gaussian, VALID.
// R6: field-packed float2 pipeline.
//  - Only 4 field channels needed: SSIM uses s11+s22, never s11/s22 alone.
//    vbA = (m1, m2), vbB = (s11+s22, s12). Packed v_pk_fma halves FMA issue.
//  - TI_C=128 (2 full waves of cols), TO_R=16 (2 strips of 8): phase 1 is
//    exactly ONE item per thread (R5 wasted a 10/64-lane second round).
//  - LDS 33KB -> 4 blocks/CU (was 49.6KB -> 3): 16 waves/CU.
//  - float2 stride 129 (===1 mod 16): phase-2 b64 reads uniform over bank
//    pairs (4 lanes each = b64 minimum); phase-1 writes lane-consecutive.

#define WIN   11
#define IMG   512
#define OUT_N 502
#define TO_R  16                 // output rows per block (2 strips of 8)
#define TO_C  118                // output cols per block
#define TI_C  128                // input cols = 2 waves
#define VB_W  129                // float2 row stride, ===1 mod 16
#define C1F   6.5025f
#define C2F   58.5225f

struct GaussW { float w[WIN]; };

__device__ __forceinline__ float2 f2(float a, float b) { return make_float2(a, b); }
__device__ __forceinline__ float2 operator+(float2 a, float2 b) { return f2(a.x+b.x, a.y+b.y); }
__device__ __forceinline__ float2 operator*(float2 a, float2 b) { return f2(a.x*b.x, a.y*b.y); }

__global__ __launch_bounds__(256) void ssim_v6_kernel(
    const float* __restrict__ X, const float* __restrict__ Y,
    GaussW gw, double* __restrict__ acc)
{
    __shared__ float2 vbA[TO_R][VB_W];   // (m1, m2)        16512 B
    __shared__ float2 vbB[TO_R][VB_W];   // (s11+s22, s12)  16512 B

    const int plane = blockIdx.z;
    const int ox0 = blockIdx.x * TO_C;
    const int oy0 = blockIdx.y * TO_R;
    const float* Xp = X + (size_t)plane * IMG * IMG;
    const float* Yp = Y + (size_t)plane * IMG * IMG;
    const int tid  = threadIdx.x;
    const int wave = tid >> 6;
    const int lane = tid & 63;

    // ---- Phase 1: vertical 11-tap, exactly one (strip, col) per thread ----
    {
        const int s  = wave >> 1;             // strip 0..1 (8 output rows)
        const int c  = ((wave & 1) << 6) | lane;   // col 0..127
        int gc = ox0 + c; if (gc > IMG - 1) gc = IMG - 1;
        const int r0 = oy0 + s * 8;

        float2 a01[8], aB[8];
#pragma unroll
        for (int j = 0; j < 8; ++j) { a01[j] = f2(0.f, 0.f); aB[j] = f2(0.f, 0.f); }

#pragma unroll
        for (int k = 0; k < 18; ++k) {        // 8 outputs need 18 input rows
            int gr = r0 + k; if (gr > IMG - 1) gr = IMG - 1;
            size_t off = (size_t)gr * IMG + gc;
            float x = Xp[off];
            float y = Yp[off];
            float2 xy  = f2(x, y);
            float2 sq  = xy * xy;                 // (xx, yy) packed
            float2 pb  = f2(sq.x + sq.y, x * y);  // (xx+yy, xy)
            const int jlo = (k > 10) ? (k - 10) : 0;
            const int jhi = (k < 7) ? k : 7;
#pragma unroll
            for (int j = jlo; j <= jhi; ++j) {
                float wv = gw.w[k - j];
                float2 wv2 = f2(wv, wv);
                a01[j] = a01[j] + wv2 * xy;       // v_pk_fma
                aB[j]  = aB[j]  + wv2 * pb;       // v_pk_fma
            }
        }
#pragma unroll
        for (int j = 0; j < 8; ++j) {             // lane-consecutive b64 stores
            int i = s * 8 + j;
            vbA[i][c] = a01[j];
            vbB[i][c] = aB[j];
        }
    }
    __syncthreads();

    // ---- Phase 2: horizontal 11-tap + SSIM, 8 outputs/thread ----
    // i = tid&15 (row), g = tid>>4 (col-group), cols 8g..8g+7.
    const int i  = tid & 15;
    const int g  = tid >> 4;
    const int c0 = 8 * g;
    const int gi = oy0 + i;
    float psum = 0.f;

    {
        float2 v01[18], vB[18];
#pragma unroll
        for (int k = 0; k < 18; ++k) {
            int cq = c0 + k; if (cq > TI_C) cq = TI_C;  // only g=15 clamps; its outputs are masked
            v01[k] = vbA[i][cq];
            vB[k]  = vbB[i][cq];
        }
        float2 m01[8], mB[8];
#pragma unroll
        for (int oc = 0; oc < 8; ++oc) { m01[oc] = f2(0.f,0.f); mB[oc] = f2(0.f,0.f); }
#pragma unroll
        for (int k = 0; k < WIN; ++k) {
            float2 wv2 = f2(gw.w[k], gw.w[k]);
#pragma unroll
            for (int oc = 0; oc < 8; ++oc) {
                m01[oc] = m01[oc] + wv2 * v01[oc + k];   // v_pk_fma
                mB[oc]  = mB[oc]  + wv2 * vB[oc + k];    // v_pk_fma
            }
        }
        if (gi < OUT_N) {
#pragma unroll
            for (int oc = 0; oc < 8; ++oc) {
                int lc = c0 + oc;
                int gj = ox0 + lc;
                if (lc < TO_C && gj < OUT_N) {
                    float m1 = m01[oc].x, m2 = m01[oc].y;
                    float S  = mB[oc].x,  s12 = mB[oc].y;
                    float mu12 = m1 * m2;
                    float musq = m1 * m1 + m2 * m2;
                    float sig12 = s12 - mu12;
                    float sigsum = S - musq;
                    float num = (2.f * mu12 + C1F) * (2.f * sig12 + C2F);
                    float den = (musq + C1F) * (sigsum + C2F);
                    num = fmaxf(num, 0.f);
                    psum += num * __builtin_amdgcn_rcpf(den);
                }
            }
        }
    }

    // ---- block reduction ----
#pragma unroll
    for (int off = 32; off > 0; off >>= 1)
        psum += __shfl_down(psum, off, 64);
    __shared__ float wsum[4];
    if ((tid & 63) == 0) wsum[tid >> 6] = psum;
    __syncthreads();
    if (tid == 0) {
        float s = wsum[0] + wsum[1] + wsum[2] + wsum[3];
        atomicAdd(acc, (double)s);
    }
}

__global__ void ssim_finalize_kernel(const double* __restrict__ acc,
                                     float* __restrict__ out)
{
    if (threadIdx.x == 0 && blockIdx.x == 0) {
        const double count = (double)96 * OUT_N * OUT_N;
        out[0] = (float)(1.0 - (*acc) / count);
    }
}

extern "C" void kernel_launch(void* const* d_in, const int* in_sizes, int n_in,
                              void* d_out, int out_size, void* d_ws, size_t ws_size,
                              hipStream_t stream) {
    (void)in_sizes; (void)n_in; (void)out_size; (void)ws_size;
    const float* X = (const float*)d_in[0];
    const float* Y = (const float*)d_in[1];
    float* out = (float*)d_out;
    double* acc = (double*)d_ws;

    hipMemsetAsync(d_ws, 0, sizeof(double), stream);

    GaussW gw;
    {
        double g[WIN], s = 0.0;
        for (int i = 0; i < WIN; ++i) {
            double d = (double)(i - 5);
            g[i] = exp(-(d * d) / (2.0 * 1.5 * 1.5));
            s += g[i];
        }
        for (int i = 0; i < WIN; ++i) gw.w[i] = (float)(g[i] / s);
    }

    dim3 grid((OUT_N + TO_C - 1) / TO_C,   // 5
              (OUT_N + TO_R - 1) / TO_R,   // 32
              96);
    ssim_v6_kernel<<<grid, 256, 0, stream>>>(X, Y, gw, acc);
    ssim_finalize_kernel<<<1, 64, 0, stream>>>(acc, out);
}